// Round 7
// baseline (2123.545 us; speedup 1.0000x reference)
//
#include <hip/hip_runtime.h>
#include <hip/hip_bf16.h>

#define DT 0.1f
#define TAU_HP 12.3f
#define TAU_LP 2.3f
#define SCAN_B 1024
#define MWMAX 6400         // LDS mask words (supports n_neurons <= 204800)

// ---------------------------------------------------------------------------
// R1-R4: CSR-by-target, fused per-step kernel, Tm1-target edges dropped.
// R5: 1 thr/Tm1 row + 8 lanes/gather row. NEUTRAL (1876 vs 1836)
//     -> step is NOT wave-slot-bound.
// R6: cooperative all-steps kernel. 9457us (5x WORSE). REVERTED.
// R7: relu-bitmask skip w/ GLOBAL mask reads. 2179us (+16%): per-edge mask
//     load was itself a VMEM op on the bottlenecked path.
// R8: mask in LDS. 1779us (WIN, -100us): ds_read bit-test off the VMEM path.
//     But gather predication saved only ~2us/step -> TA processes masked
//     lanes anyway; step is VMEM-request-processing bound, not bytes-bound.
// R9: build rewritten: 3-pass bucket-radix (bhist+bin+finalize, ~380us,
//     bin alone 135us w/ 3.4x write amp) -> full-resolution global-atomic
//     histogram + scan + ONE direct scatter pass. Global atomicAdd on a
//     200K-counter array is L2-resident and cheap; saves two full passes
//     over the edge list. Side effect: top-5 dispatches will now include
//     step_kernel -> first steady-state counters. step_kernel unchanged.
// ---------------------------------------------------------------------------

__global__ void init_kernel(float* __restrict__ vA,
                            float* __restrict__ tm1_f,
                            unsigned* __restrict__ mask3,
                            int* __restrict__ row_start,
                            int n_neurons, int n_tm1, int mask3_words) {
    int i = blockIdx.x * blockDim.x + threadIdx.x;
    if (i < n_neurons) vA[i] = 0.0f;
    if (i < n_tm1) tm1_f[i] = 0.0f;
    if (i < mask3_words) mask3[i] = 0u;
    if (i <= n_neurons) row_start[i] = 0;    // histogram accumulator
}

// --- build pass 1: full-resolution histogram (Tm1 targets dropped) ----------
__global__ void ghist_kernel(const int* __restrict__ tgt, int* __restrict__ hist,
                             int n_edges, int n_tm1) {
    int stride = gridDim.x * blockDim.x;
    for (int i = blockIdx.x * blockDim.x + threadIdx.x; i < n_edges; i += stride) {
        int t = tgt[i];
        if (t >= n_tm1) atomicAdd(&hist[t], 1);   // L2-resident, random -> low conflict
    }
}

// --- 3-level exclusive scan (over n_neurons counters, in-place) --------------
__global__ void scan1_kernel(const int* in, int* out, int* bsums, int n) {
    __shared__ int s[SCAN_B];
    int gid = blockIdx.x * SCAN_B + threadIdx.x;
    int x = (gid < n) ? in[gid] : 0;
    s[threadIdx.x] = x;
    __syncthreads();
    for (int off = 1; off < SCAN_B; off <<= 1) {
        int t = (threadIdx.x >= off) ? s[threadIdx.x - off] : 0;
        __syncthreads();
        s[threadIdx.x] += t;
        __syncthreads();
    }
    if (gid < n) out[gid] = s[threadIdx.x] - x;       // exclusive
    if (threadIdx.x == SCAN_B - 1) bsums[blockIdx.x] = s[SCAN_B - 1];
}

__global__ void scan2_kernel(int* bsums, int nb, int* total) {
    __shared__ int s[SCAN_B];
    int x = (threadIdx.x < nb) ? bsums[threadIdx.x] : 0;
    s[threadIdx.x] = x;
    __syncthreads();
    for (int off = 1; off < SCAN_B; off <<= 1) {
        int t = (threadIdx.x >= off) ? s[threadIdx.x - off] : 0;
        __syncthreads();
        s[threadIdx.x] += t;
        __syncthreads();
    }
    if (threadIdx.x == nb - 1) *total = s[threadIdx.x];   // inclusive grand total
    if (threadIdx.x < nb) bsums[threadIdx.x] = s[threadIdx.x] - x;
}

__global__ void scanadd_kernel(int* data, const int* __restrict__ bsums, int n) {
    int gid = blockIdx.x * blockDim.x + threadIdx.x;
    if (gid < n) data[gid] += bsums[gid / SCAN_B];
}

// --- copy row_start -> scatter cursors; finish row_start tail ----------------
__global__ void mkcur_kernel(const int* __restrict__ row_start,
                             int* __restrict__ cur,
                             int* __restrict__ rs_tail,
                             const int* __restrict__ total, int n_neurons) {
    int i = blockIdx.x * blockDim.x + threadIdx.x;
    if (i < n_neurons) cur[i] = row_start[i];
    if (i == 0) *rs_tail = *total;           // row_start[n_neurons] = n_kept
}

// --- build pass 2: ONE direct scatter to final CSR position ------------------
// record = (src, weight-bits). Within-row order is arrival order
// (nondeterministic — summation order within a row was already
// nondeterministic in the radix build; tolerance-covered).
__global__ void scatter_kernel(const int* __restrict__ src,
                               const int* __restrict__ tgt,
                               const float* __restrict__ w,
                               int* __restrict__ cur,
                               int2* __restrict__ edges,
                               int n_edges, int n_tm1) {
    int stride = gridDim.x * blockDim.x;
    for (int i = blockIdx.x * blockDim.x + threadIdx.x; i < n_edges; i += stride) {
        int t = tgt[i];
        if (t < n_tm1) continue;             // dead edges (dv[:tm1]=0)
        int pos = atomicAdd(&cur[t], 1);
        edges[pos] = make_int2(src[i], __float_as_int(w[i]));
    }
}

// --- fused per-step kernel (LDS relu-bitmask skip) ---------------------------
// Thread map: [0, gbase)               -> Tm1 region (1 thr/row + pads)
//             [gbase, gbase + 8*nrows) -> 8 lanes per gather row
// gbase mult of 64 -> every wave is entirely Tm1-region or gather-region.
// Blocks containing any gather thread stage the 25KB activity mask into LDS
// (uniform per-block branch), then bit-tests are ds_reads off the VMEM path.
__global__ __launch_bounds__(1024)
void step_kernel(const int* __restrict__ row_start,
                 const int2* __restrict__ edges,
                 const float* __restrict__ vr,
                 float* __restrict__ vw,
                 float* __restrict__ tm1_f,
                 const float* __restrict__ x,     // tm1_input + k*n_tm1
                 const float* __restrict__ tau,
                 const float* __restrict__ vrest,
                 const unsigned* __restrict__ maskR,
                 unsigned* __restrict__ maskW,
                 unsigned* __restrict__ maskC,
                 int mask_words,
                 int n_neurons, int n_tm1, int gbase, int last) {
    __shared__ unsigned smask[MWMAX];
    int g = blockIdx.x * blockDim.x + threadIdx.x;

    // uniform per-block: does this block contain gather threads?
    if ((int)((blockIdx.x + 1) * blockDim.x) > gbase) {
        for (int i = threadIdx.x; i < mask_words; i += blockDim.x)
            smask[i] = maskR[i];
        __syncthreads();
    }

    if (g < gbase) {                         // Tm1 region (wave-uniform branch)
        if (g < mask_words) maskC[g] = 0u;   // clear the idle buffer for step k+1
        float val = 0.0f;
        bool wrote = false;
        if (g < n_tm1) {
            float cur = vr[g];               // = tm1_v at step k
            if (last) {
                val = cur;                   // ref: v[:tm1] = old tm1_v
            } else {
                float f  = tm1_f[g];
                float xk = x[g];
                float hp = xk - f;
                tm1_f[g] = f + DT * (xk - f) / TAU_HP;
                val = cur + DT * (fmaxf(hp, 0.0f) - cur) / TAU_LP;
            }
            vw[g] = val;
            wrote = true;
        }
        // ballot mask write: 64 consecutive ids per wave, 2 words
        unsigned long long bm = __ballot(wrote && (val > 0.0f));
        int l = threadIdx.x & 63;
        unsigned lo = (unsigned)(bm & 0xffffffffull);
        unsigned hi = (unsigned)(bm >> 32);
        if (l == 0 && lo)  atomicOr(&maskW[g >> 5], lo);
        if (l == 32 && hi) atomicOr(&maskW[g >> 5], hi);
        return;
    }

    int t = g - gbase;
    int row = n_tm1 + (t >> 3);
    int lane = t & 7;
    bool active = (row < n_neurons);
    float sum = 0.0f;
    float vnew = 0.0f;

    if (active) {
        int s = row_start[row];
        int e = row_start[row + 1];
        for (int p = (s & ~1) + 2 * lane; p < e; p += 16) {
            int4 q = *(const int4*)(edges + p);  // 16B aligned (p even)
            // bit==1 implies vr>0 -> relu redundant; bit==0 -> term exactly 0
            bool a0 = (p >= s)    && ((smask[(unsigned)q.x >> 5] >> (q.x & 31)) & 1u);
            bool a1 = (p + 1 < e) && ((smask[(unsigned)q.z >> 5] >> (q.z & 31)) & 1u);
            if (a0) sum += vr[q.x] * __int_as_float(q.y);
            if (a1) sum += vr[q.z] * __int_as_float(q.w);
        }
    }
    sum += __shfl_xor(sum, 4);
    sum += __shfl_xor(sum, 2);
    sum += __shfl_xor(sum, 1);
    if (active && lane == 0) {
        float vi = vr[row];
        vnew = vi + DT * ((-vi + sum + vrest[row]) / tau[row]);
        vw[row] = vnew;
    }
    // wave-level mask write: 8 rows/wave at bit offset (row0&31) in {0,8,16,24}
    unsigned long long bm = __ballot(active && lane == 0 && vnew > 0.0f);
    if ((threadIdx.x & 63) == 0) {
        unsigned b8 = 0;
        #pragma unroll
        for (int i = 0; i < 8; ++i) b8 |= (unsigned)((bm >> (8 * i)) & 1ull) << i;
        if (b8) {
            int row0 = n_tm1 + (t >> 3);     // this lane's row = wave's first row
            atomicOr(&maskW[row0 >> 5], b8 << (row0 & 31));
        }
    }
}

extern "C" void kernel_launch(void* const* d_in, const int* in_sizes, int n_in,
                              void* d_out, int out_size, void* d_ws, size_t ws_size,
                              hipStream_t stream) {
    const float* tm1_input  = (const float*)d_in[0];
    const float* weights    = (const float*)d_in[1];
    const float* tau        = (const float*)d_in[2];
    const float* vrest      = (const float*)d_in[3];
    const int*   source_idx = (const int*)d_in[4];
    const int*   target_idx = (const int*)d_in[5];

    const int n_edges   = in_sizes[1];
    const int n_neurons = in_sizes[2];
    const int n_tm1     = 25000;
    const int steps     = in_sizes[0] / n_tm1;

    const int mask_words = (n_neurons + 31) >> 5;            // 6250 <= MWMAX

    // Workspace (4-byte units). edges first -> 16B aligned for int4 gather.
    size_t off = 0;
    auto alloc = [&](size_t n) { size_t o = off; off += n; return o; };
    int* ws_i = (int*)d_ws;
    float* ws_f = (float*)d_ws;

    int2*     edges     = (int2*)(ws_i + alloc((size_t)(n_edges + 2) * 2));
    float*    vA        = ws_f + alloc(n_neurons);
    float*    vB        = ws_f + alloc(n_neurons);
    float*    tm1_f     = ws_f + alloc(n_tm1);
    int*      row_start = ws_i + alloc(n_neurons + 1);
    int*      cur       = ws_i + alloc(n_neurons);
    unsigned* mask3     = (unsigned*)(ws_i + alloc((size_t)3 * mask_words));
    int*      bsums     = ws_i + alloc(SCAN_B);
    int*      total     = ws_i + alloc(1);
    (void)ws_size;

    float* out = (float*)d_out;

    const int B = 256;
    const int gridN = (n_neurons + 1 + B - 1) / B;
    const int nScanBlocks = (n_neurons + SCAN_B - 1) / SCAN_B;  // 196 <= 1024
    const int gridSA = (n_neurons + B - 1) / B;
    const int gridE = 2048;                                  // grid-stride passes

    // Step-kernel thread map: Tm1 rows 1:1, then wave-aligned 8-lane groups.
    const int SB = 1024;
    const int gbase = (n_tm1 + 63) & ~63;
    const int work  = gbase + (n_neurons - n_tm1) * 8;
    const int gridG = (work + SB - 1) / SB;

    // --- one-time (per launch) CSR build: hist -> scan -> direct scatter ---
    init_kernel<<<gridN, B, 0, stream>>>(vA, tm1_f, mask3, row_start,
                                         n_neurons, n_tm1, 3 * mask_words);
    ghist_kernel<<<gridE, B, 0, stream>>>(target_idx, row_start, n_edges, n_tm1);
    scan1_kernel<<<nScanBlocks, SCAN_B, 0, stream>>>(row_start, row_start, bsums,
                                                     n_neurons);
    scan2_kernel<<<1, SCAN_B, 0, stream>>>(bsums, nScanBlocks, total);
    scanadd_kernel<<<gridSA, B, 0, stream>>>(row_start, bsums, n_neurons);
    mkcur_kernel<<<gridSA, B, 0, stream>>>(row_start, cur, row_start + n_neurons,
                                           total, n_neurons);
    scatter_kernel<<<gridE, B, 0, stream>>>(source_idx, target_idx, weights,
                                            cur, edges, n_edges, n_tm1);

    // --- steps: ONE fused kernel per step, double-buffered v, rotating mask ---
    for (int k = 0; k < steps; ++k) {
        const float* vr = (k & 1) ? vB : vA;
        float* vw = (k == steps - 1) ? out : ((k & 1) ? vA : vB);
        unsigned* mW = mask3 + (size_t)(k % 3) * mask_words;
        unsigned* mR = mask3 + (size_t)((k + 2) % 3) * mask_words;
        unsigned* mC = mask3 + (size_t)((k + 1) % 3) * mask_words;
        step_kernel<<<gridG, SB, 0, stream>>>(
            row_start, edges, vr, vw, tm1_f,
            tm1_input + (size_t)k * n_tm1,
            tau, vrest, mR, mW, mC, mask_words,
            n_neurons, n_tm1, gbase, (k == steps - 1) ? 1 : 0);
    }
}

// Round 8
// 1827.883 us; speedup vs baseline: 1.1618x; 1.1618x over previous
//
#include <hip/hip_runtime.h>
#include <hip/hip_bf16.h>

#define DT 0.1f
#define TAU_HP 12.3f
#define TAU_LP 2.3f
#define SCAN_B 1024

// Radix-build parameters: bucket = tgt >> BSHIFT (128 targets/bucket).
#define BSHIFT 7
#define BMASK 127
#define BMAX 2048          // max buckets supported (n_neurons <= 262144)
#define CHUNK 65536        // edges per block in hist/bin passes (R10: was 32768)
#define B4_CAP 6144        // max records per bucket in finalize
#define MWMAX 6400         // LDS mask words (supports n_neurons <= 204800)

// ---------------------------------------------------------------------------
// R1-R4: CSR-by-target, zero-atomic radix build, fused per-step kernel,
//        Tm1-target edges dropped.
// R5: 1 thr/Tm1 row + 8 lanes/gather row. NEUTRAL (1876 vs 1836)
//     -> step is NOT wave-slot-bound.
// R6: cooperative all-steps kernel. 9457us (5x WORSE). REVERTED.
// R7: relu-bitmask skip w/ GLOBAL mask reads. 2179us (+16%): per-edge mask
//     load was a VMEM op on the bottlenecked path.
// R8: mask in LDS. 1779us (WIN): ds_read bit-test off the VMEM path. Gather
//     predication itself saved ~nothing -> step is VMEM-request-processing /
//     L2-random-read bound, not bytes-bound.
// R9: direct global-atomic scatter build. 2123us (FAILED falsifier: scatter
//     316us, WRITE_SIZE 346MB = 7.7x amp). REVERTED to radix build.
// R10: revert to R8 + CHUNK 32K->64K (bhist/bin): doubles records per
//     bucket per block (~21->~42, 168B->336B contiguous per bucket-block)
//     -> roughly halves partial-line write amplification in bin; also
//     halves n_scan. Step kernel identical to R8.
// ---------------------------------------------------------------------------

__global__ void init_kernel(float* __restrict__ vA,
                            float* __restrict__ tm1_f,
                            unsigned* __restrict__ mask3,
                            int n_neurons, int n_tm1, int mask3_words) {
    int i = blockIdx.x * blockDim.x + threadIdx.x;
    if (i < n_neurons) vA[i] = 0.0f;
    if (i < n_tm1) tm1_f[i] = 0.0f;
    if (i < mask3_words) mask3[i] = 0u;
}

// --- build pass 1: per-(block,bucket) histogram (Tm1 targets dropped) --------
__global__ void bhist_kernel(const int* __restrict__ tgt, int* __restrict__ blkhist,
                             int n_edges, int n_tm1, int nb, int nblk) {
    __shared__ int hist[BMAX];
    int b = blockIdx.x;
    for (int i = threadIdx.x; i < nb; i += blockDim.x) hist[i] = 0;
    __syncthreads();
    int base = b * CHUNK;
    int end = min(base + CHUNK, n_edges);
    for (int k = base + threadIdx.x; k < end; k += blockDim.x) {
        int t = tgt[k];
        if (t >= n_tm1) atomicAdd(&hist[t >> BSHIFT], 1);
    }
    __syncthreads();
    for (int i = threadIdx.x; i < nb; i += blockDim.x)
        blkhist[(size_t)i * nblk + b] = hist[i];      // bucket-major for scan
}

// --- 3-level exclusive scan --------------------------------------------------
__global__ void scan1_kernel(const int* in, int* out, int* bsums, int n) {
    __shared__ int s[SCAN_B];
    int gid = blockIdx.x * SCAN_B + threadIdx.x;
    int x = (gid < n) ? in[gid] : 0;
    s[threadIdx.x] = x;
    __syncthreads();
    for (int off = 1; off < SCAN_B; off <<= 1) {
        int t = (threadIdx.x >= off) ? s[threadIdx.x - off] : 0;
        __syncthreads();
        s[threadIdx.x] += t;
        __syncthreads();
    }
    if (gid < n) out[gid] = s[threadIdx.x] - x;       // exclusive
    if (threadIdx.x == SCAN_B - 1) bsums[blockIdx.x] = s[SCAN_B - 1];
}

__global__ void scan2_kernel(int* bsums, int nb, int* total) {
    __shared__ int s[SCAN_B];
    int x = (threadIdx.x < nb) ? bsums[threadIdx.x] : 0;
    s[threadIdx.x] = x;
    __syncthreads();
    for (int off = 1; off < SCAN_B; off <<= 1) {
        int t = (threadIdx.x >= off) ? s[threadIdx.x - off] : 0;
        __syncthreads();
        s[threadIdx.x] += t;
        __syncthreads();
    }
    if (threadIdx.x == nb - 1) *total = s[threadIdx.x];   // inclusive grand total
    if (threadIdx.x < nb) bsums[threadIdx.x] = s[threadIdx.x] - x;
}

__global__ void scanadd_kernel(int* data, const int* __restrict__ bsums, int n) {
    int gid = blockIdx.x * blockDim.x + threadIdx.x;
    if (gid < n) data[gid] += bsums[gid / SCAN_B];
}

// --- build pass 2: bin kept edges into bucket order (LDS cursors) ------------
// record = (src | tlow<<18, weight-bits); src < 2^18, tlow 7 bits.
__global__ void bin_kernel(const int* __restrict__ src, const int* __restrict__ tgt,
                           const float* __restrict__ w, const int* __restrict__ scanned,
                           int2* __restrict__ edges, int n_edges, int n_tm1,
                           int nb, int nblk) {
    __shared__ int cur[BMAX];
    int b = blockIdx.x;
    for (int i = threadIdx.x; i < nb; i += blockDim.x)
        cur[i] = scanned[(size_t)i * nblk + b];
    __syncthreads();
    int base = b * CHUNK;
    int end = min(base + CHUNK, n_edges);
    for (int k = base + threadIdx.x; k < end; k += blockDim.x) {
        int t = tgt[k];
        if (t < n_tm1) continue;                      // dead edges (dv[:tm1]=0)
        int pos = atomicAdd(&cur[t >> BSHIFT], 1);    // LDS atomic
        edges[pos] = make_int2(src[k] | ((t & BMASK) << 18), __float_as_int(w[k]));
    }
}

// --- build pass 3: per-bucket finalize, entirely in LDS, in-place ------------
__global__ void finalize_kernel(int2* edges, const int* __restrict__ scanned,
                                int* __restrict__ row_start,
                                const int* __restrict__ total,
                                int n_neurons, int nb, int nblk) {
    __shared__ int2 buf[B4_CAP];
    __shared__ int hist[BMASK + 1], ls[BMASK + 1], cur[BMASK + 1];
    int b = blockIdx.x;
    int n_kept = *total;
    int beg = scanned[(size_t)b * nblk];
    int end = (b == nb - 1) ? n_kept : scanned[(size_t)(b + 1) * nblk];
    int n = min(end - beg, B4_CAP);

    for (int k = threadIdx.x; k < n; k += blockDim.x) buf[k] = edges[beg + k];
    if (threadIdx.x <= BMASK) hist[threadIdx.x] = 0;
    __syncthreads();
    for (int k = threadIdx.x; k < n; k += blockDim.x)
        atomicAdd(&hist[(buf[k].x >> 18) & BMASK], 1);
    __syncthreads();
    if (threadIdx.x <= BMASK) ls[threadIdx.x] = hist[threadIdx.x];
    __syncthreads();
    for (int off = 1; off <= BMASK; off <<= 1) {
        int t = (threadIdx.x <= BMASK && threadIdx.x >= off) ? ls[threadIdx.x - off] : 0;
        __syncthreads();
        if (threadIdx.x <= BMASK) ls[threadIdx.x] += t;   // inclusive
        __syncthreads();
    }
    if (threadIdx.x <= BMASK) {
        int excl = ls[threadIdx.x] - hist[threadIdx.x];
        cur[threadIdx.x] = excl;
        int t = (b << BSHIFT) + threadIdx.x;
        if (t < n_neurons) row_start[t] = beg + excl;
    }
    if (b == nb - 1 && threadIdx.x == 0) row_start[n_neurons] = n_kept;
    __syncthreads();
    for (int k = threadIdx.x; k < n; k += blockDim.x) {
        int2 r = buf[k];
        int pos = atomicAdd(&cur[(r.x >> 18) & BMASK], 1);  // LDS atomic
        edges[beg + pos] = make_int2(r.x & 0x3FFFF, r.y);
    }
}

// --- fused per-step kernel (LDS relu-bitmask skip) ---------------------------
// Thread map: [0, gbase)               -> Tm1 region (1 thr/row + pads)
//             [gbase, gbase + 8*nrows) -> 8 lanes per gather row
// gbase mult of 64 -> every wave is entirely Tm1-region or gather-region.
// Blocks containing any gather thread stage the 25KB activity mask into LDS
// (uniform per-block branch), then bit-tests are ds_reads off the VMEM path.
__global__ __launch_bounds__(1024)
void step_kernel(const int* __restrict__ row_start,
                 const int2* __restrict__ edges,
                 const float* __restrict__ vr,
                 float* __restrict__ vw,
                 float* __restrict__ tm1_f,
                 const float* __restrict__ x,     // tm1_input + k*n_tm1
                 const float* __restrict__ tau,
                 const float* __restrict__ vrest,
                 const unsigned* __restrict__ maskR,
                 unsigned* __restrict__ maskW,
                 unsigned* __restrict__ maskC,
                 int mask_words,
                 int n_neurons, int n_tm1, int gbase, int last) {
    __shared__ unsigned smask[MWMAX];
    int g = blockIdx.x * blockDim.x + threadIdx.x;

    // uniform per-block: does this block contain gather threads?
    if ((int)((blockIdx.x + 1) * blockDim.x) > gbase) {
        for (int i = threadIdx.x; i < mask_words; i += blockDim.x)
            smask[i] = maskR[i];
        __syncthreads();
    }

    if (g < gbase) {                         // Tm1 region (wave-uniform branch)
        if (g < mask_words) maskC[g] = 0u;   // clear the idle buffer for step k+1
        float val = 0.0f;
        bool wrote = false;
        if (g < n_tm1) {
            float cur = vr[g];               // = tm1_v at step k
            if (last) {
                val = cur;                   // ref: v[:tm1] = old tm1_v
            } else {
                float f  = tm1_f[g];
                float xk = x[g];
                float hp = xk - f;
                tm1_f[g] = f + DT * (xk - f) / TAU_HP;
                val = cur + DT * (fmaxf(hp, 0.0f) - cur) / TAU_LP;
            }
            vw[g] = val;
            wrote = true;
        }
        // ballot mask write: 64 consecutive ids per wave, 2 words
        unsigned long long bm = __ballot(wrote && (val > 0.0f));
        int l = threadIdx.x & 63;
        unsigned lo = (unsigned)(bm & 0xffffffffull);
        unsigned hi = (unsigned)(bm >> 32);
        if (l == 0 && lo)  atomicOr(&maskW[g >> 5], lo);
        if (l == 32 && hi) atomicOr(&maskW[g >> 5], hi);
        return;
    }

    int t = g - gbase;
    int row = n_tm1 + (t >> 3);
    int lane = t & 7;
    bool active = (row < n_neurons);
    float sum = 0.0f;
    float vnew = 0.0f;

    if (active) {
        int s = row_start[row];
        int e = row_start[row + 1];
        for (int p = (s & ~1) + 2 * lane; p < e; p += 16) {
            int4 q = *(const int4*)(edges + p);  // 16B aligned (p even)
            // bit==1 implies vr>0 -> relu redundant; bit==0 -> term exactly 0
            bool a0 = (p >= s)    && ((smask[(unsigned)q.x >> 5] >> (q.x & 31)) & 1u);
            bool a1 = (p + 1 < e) && ((smask[(unsigned)q.z >> 5] >> (q.z & 31)) & 1u);
            if (a0) sum += vr[q.x] * __int_as_float(q.y);
            if (a1) sum += vr[q.z] * __int_as_float(q.w);
        }
    }
    sum += __shfl_xor(sum, 4);
    sum += __shfl_xor(sum, 2);
    sum += __shfl_xor(sum, 1);
    if (active && lane == 0) {
        float vi = vr[row];
        vnew = vi + DT * ((-vi + sum + vrest[row]) / tau[row]);
        vw[row] = vnew;
    }
    // wave-level mask write: 8 rows/wave at bit offset (row0&31) in {0,8,16,24}
    unsigned long long bm = __ballot(active && lane == 0 && vnew > 0.0f);
    if ((threadIdx.x & 63) == 0) {
        unsigned b8 = 0;
        #pragma unroll
        for (int i = 0; i < 8; ++i) b8 |= (unsigned)((bm >> (8 * i)) & 1ull) << i;
        if (b8) {
            int row0 = n_tm1 + (t >> 3);     // this lane's row = wave's first row
            atomicOr(&maskW[row0 >> 5], b8 << (row0 & 31));
        }
    }
}

extern "C" void kernel_launch(void* const* d_in, const int* in_sizes, int n_in,
                              void* d_out, int out_size, void* d_ws, size_t ws_size,
                              hipStream_t stream) {
    const float* tm1_input  = (const float*)d_in[0];
    const float* weights    = (const float*)d_in[1];
    const float* tau        = (const float*)d_in[2];
    const float* vrest      = (const float*)d_in[3];
    const int*   source_idx = (const int*)d_in[4];
    const int*   target_idx = (const int*)d_in[5];

    const int n_edges   = in_sizes[1];
    const int n_neurons = in_sizes[2];
    const int n_tm1     = 25000;
    const int steps     = in_sizes[0] / n_tm1;

    const int nb   = (n_neurons + BMASK) >> BSHIFT;          // 1563 buckets
    const int nblk = (n_edges + CHUNK - 1) / CHUNK;          // 98 blocks
    const int n_scan = nb * nblk;                            // 153,174
    const int mask_words = (n_neurons + 31) >> 5;            // 6250 <= MWMAX

    // Workspace (4-byte units). edges first -> 16B aligned for int4 gather.
    size_t off = 0;
    auto alloc = [&](size_t n) { size_t o = off; off += n; return o; };
    int* ws_i = (int*)d_ws;
    float* ws_f = (float*)d_ws;

    int2*     edges     = (int2*)(ws_i + alloc((size_t)(n_edges + 2) * 2));
    float*    vA        = ws_f + alloc(n_neurons);
    float*    vB        = ws_f + alloc(n_neurons);
    float*    tm1_f     = ws_f + alloc(n_tm1);
    int*      row_start = ws_i + alloc(n_neurons + 1);
    unsigned* mask3     = (unsigned*)(ws_i + alloc((size_t)3 * mask_words));
    int*      blkhist   = ws_i + alloc((size_t)n_scan);
    int*      bsums     = ws_i + alloc(SCAN_B);
    int*      total     = ws_i + alloc(1);
    (void)ws_size;

    float* out = (float*)d_out;

    const int B = 256;
    const int gridN = (n_neurons + B - 1) / B;
    const int nScanBlocks = (n_scan + SCAN_B - 1) / SCAN_B;  // 150 <= 1024
    const int gridSA = (n_scan + B - 1) / B;

    // Step-kernel thread map: Tm1 rows 1:1, then wave-aligned 8-lane groups.
    const int SB = 1024;
    const int gbase = (n_tm1 + 63) & ~63;
    const int work  = gbase + (n_neurons - n_tm1) * 8;
    const int gridG = (work + SB - 1) / SB;

    // --- one-time (per launch) CSR build: zero global atomics ---
    init_kernel<<<gridN, B, 0, stream>>>(vA, tm1_f, mask3, n_neurons, n_tm1,
                                         3 * mask_words);
    bhist_kernel<<<nblk, 1024, 0, stream>>>(target_idx, blkhist, n_edges, n_tm1,
                                            nb, nblk);
    scan1_kernel<<<nScanBlocks, SCAN_B, 0, stream>>>(blkhist, blkhist, bsums, n_scan);
    scan2_kernel<<<1, SCAN_B, 0, stream>>>(bsums, nScanBlocks, total);
    scanadd_kernel<<<gridSA, B, 0, stream>>>(blkhist, bsums, n_scan);
    bin_kernel<<<nblk, 1024, 0, stream>>>(source_idx, target_idx, weights, blkhist,
                                          edges, n_edges, n_tm1, nb, nblk);
    finalize_kernel<<<nb, 1024, 0, stream>>>(edges, blkhist, row_start, total,
                                             n_neurons, nb, nblk);

    // --- steps: ONE fused kernel per step, double-buffered v, rotating mask ---
    for (int k = 0; k < steps; ++k) {
        const float* vr = (k & 1) ? vB : vA;
        float* vw = (k == steps - 1) ? out : ((k & 1) ? vA : vB);
        unsigned* mW = mask3 + (size_t)(k % 3) * mask_words;
        unsigned* mR = mask3 + (size_t)((k + 2) % 3) * mask_words;
        unsigned* mC = mask3 + (size_t)((k + 1) % 3) * mask_words;
        step_kernel<<<gridG, SB, 0, stream>>>(
            row_start, edges, vr, vw, tm1_f,
            tm1_input + (size_t)k * n_tm1,
            tau, vrest, mR, mW, mC, mask_words,
            n_neurons, n_tm1, gbase, (k == steps - 1) ? 1 : 0);
    }
}